// Round 4
// baseline (5008.303 us; speedup 1.0000x reference)
//
#include <hip/hip_runtime.h>
#include <hip/hip_bf16.h>
#include <math.h>

#define N_NODES 32768
#define E_EDGES 524288
#define NHID    256
#define HEAD_DIM 64
#define SEQ     512
#define EPS_LN  1e-5f

typedef __hip_bfloat16 bf16;
static const size_t NH = (size_t)N_NODES * NHID;  // 8,388,608

__device__ __forceinline__ void unpack2(unsigned int u, float& lo, float& hi) {
    union { float f; unsigned int i; } a, b;
    a.i = u << 16; b.i = u & 0xffff0000u;
    lo = a.f; hi = b.f;
}

__device__ __forceinline__ float4 load4f(const float* p) { return *(const float4*)p; }
__device__ __forceinline__ float4 load4f(const bf16* p) {
    uint2 u = *(const uint2*)p;
    float4 r;
    unpack2(u.x, r.x, r.y);
    unpack2(u.y, r.z, r.w);
    return r;
}

// ---------------- transpose 256x256 fp32: dst[c][r] = src[r][c] ----------------
__global__ void k_tr(float* __restrict__ dst, const float* __restrict__ src) {
    int r = blockIdx.x, c = threadIdx.x;
    dst[(size_t)c * 256 + r] = src[(size_t)r * 256 + c];
}

// fold BN eval-mode into scale/shift: s = g*rsqrt(v+eps), t = b - m*s
__global__ void k_bnprep(float* __restrict__ s, float* __restrict__ t,
                         const float* g, const float* b, const float* m, const float* v) {
    int c = threadIdx.x;
    float sv = g[c] * rsqrtf(v[c] + EPS_LN);
    s[c] = sv;
    t[c] = b[c] - m[c] * sv;
}

// ---------------- GEMM: C[32768 x 256] = A[32768 x 256] * W[256 x 256] (+bias), bf16 out ----
template <typename AT, typename WT>
__global__ __launch_bounds__(256) void k_gemm(const AT* __restrict__ A,
                                              const WT* __restrict__ W,
                                              const float* __restrict__ bias,
                                              bf16* __restrict__ C) {
    __shared__ float As[16][68];
    __shared__ float Ws[16][68];
    const int tid = threadIdx.x;
    const int bm = blockIdx.x * 64;
    const int bn = blockIdx.y * 64;
    const int tm = (tid & 15) << 2;
    const int tn = (tid >> 4) << 2;
    const int am = tid >> 2;          // 0..63
    const int ak = (tid & 3) << 2;    // 0,4,8,12
    const int wk = tid >> 4;          // 0..15
    const int wn = (tid & 15) << 2;   // 0..60
    float acc[4][4] = {};

    for (int k0 = 0; k0 < 256; k0 += 16) {
        const float4 av = load4f(A + (size_t)(bm + am) * 256 + k0 + ak);
        const float4 wv = load4f(W + (size_t)(k0 + wk) * 256 + bn + wn);
        As[ak + 0][am] = av.x;
        As[ak + 1][am] = av.y;
        As[ak + 2][am] = av.z;
        As[ak + 3][am] = av.w;
        *(float4*)&Ws[wk][wn] = wv;
        __syncthreads();
#pragma unroll
        for (int k = 0; k < 16; ++k) {
            const float4 a = *(const float4*)&As[k][tm];
            const float4 b = *(const float4*)&Ws[k][tn];
            acc[0][0] = fmaf(a.x, b.x, acc[0][0]);
            acc[0][1] = fmaf(a.x, b.y, acc[0][1]);
            acc[0][2] = fmaf(a.x, b.z, acc[0][2]);
            acc[0][3] = fmaf(a.x, b.w, acc[0][3]);
            acc[1][0] = fmaf(a.y, b.x, acc[1][0]);
            acc[1][1] = fmaf(a.y, b.y, acc[1][1]);
            acc[1][2] = fmaf(a.y, b.z, acc[1][2]);
            acc[1][3] = fmaf(a.y, b.w, acc[1][3]);
            acc[2][0] = fmaf(a.z, b.x, acc[2][0]);
            acc[2][1] = fmaf(a.z, b.y, acc[2][1]);
            acc[2][2] = fmaf(a.z, b.z, acc[2][2]);
            acc[2][3] = fmaf(a.z, b.w, acc[2][3]);
            acc[3][0] = fmaf(a.w, b.x, acc[3][0]);
            acc[3][1] = fmaf(a.w, b.y, acc[3][1]);
            acc[3][2] = fmaf(a.w, b.z, acc[3][2]);
            acc[3][3] = fmaf(a.w, b.w, acc[3][3]);
        }
        __syncthreads();
    }
    float4 bv = make_float4(0.f, 0.f, 0.f, 0.f);
    if (bias) bv = load4f(bias + bn + tn);
#pragma unroll
    for (int i = 0; i < 4; ++i) {
        __align__(8) bf16 tmp[4];
        tmp[0] = __float2bfloat16(acc[i][0] + bv.x);
        tmp[1] = __float2bfloat16(acc[i][1] + bv.y);
        tmp[2] = __float2bfloat16(acc[i][2] + bv.z);
        tmp[3] = __float2bfloat16(acc[i][3] + bv.w);
        *(uint2*)&C[(size_t)(bm + tm + i) * 256 + bn + tn] = *(uint2*)tmp;
    }
}

// ---------------- edge scatter: conv[dst] += attr * t[src]; one wave per edge ----------------
__global__ void k_scatter(const bf16* __restrict__ t, const int* __restrict__ esrc,
                          const int* __restrict__ edst, const float* __restrict__ eattr,
                          float* __restrict__ conv) {
    int gt = blockIdx.x * blockDim.x + threadIdx.x;
    int e = gt >> 6;
    int lane = threadIdx.x & 63;
    if (e >= E_EDGES) return;
    int s = esrc[e], d = edst[e];
    float a = eattr[e];
    uint2 u = *(const uint2*)(t + (size_t)s * 256 + lane * 4);
    float v0, v1, v2, v3;
    unpack2(u.x, v0, v1);
    unpack2(u.y, v2, v3);
    float* o = conv + (size_t)d * 256 + lane * 4;
    unsafeAtomicAdd(o + 0, a * v0);
    unsafeAtomicAdd(o + 1, a * v1);
    unsafeAtomicAdd(o + 2, a * v2);
    unsafeAtomicAdd(o + 3, a * v3);
}

// ---------------- BN apply in place (float4 over N*256 fp32) ----------------
__global__ void k_bn(float* __restrict__ conv, const float* __restrict__ s,
                     const float* __restrict__ t) {
    int gt = blockIdx.x * blockDim.x + threadIdx.x;
    size_t base = (size_t)gt * 4;
    int c = (int)(base & 255);
    float4 v = *(const float4*)(conv + base);
    const float4 sv = *(const float4*)(s + c);
    const float4 tv = *(const float4*)(t + c);
    v.x = fmaf(v.x, sv.x, tv.x);
    v.y = fmaf(v.y, sv.y, tv.y);
    v.z = fmaf(v.z, sv.z, tv.z);
    v.w = fmaf(v.w, sv.w, tv.w);
    *(float4*)(conv + base) = v;
}

// ---------------- attention: block = (graph, head, half); thread = 1 query ----------------
__global__ __launch_bounds__(256, 1) void k_attn(const bf16* __restrict__ qb,
                                                 const bf16* __restrict__ kb,
                                                 const bf16* __restrict__ vb,
                                                 bf16* __restrict__ ctx) {
    const int blk = blockIdx.x;
    const int half = blk & 1;
    const int head = (blk >> 1) & 3;
    const int b = blk >> 3;
    const int tid = threadIdx.x;
    const int q_node = b * SEQ + half * 256 + tid;

    float q[HEAD_DIM];
    {
        const bf16* qp = qb + (size_t)q_node * 256 + head * HEAD_DIM;
#pragma unroll
        for (int i = 0; i < 8; ++i) {
            uint4 u = *(const uint4*)(qp + i * 8);
            unpack2(u.x, q[i * 8 + 0], q[i * 8 + 1]);
            unpack2(u.y, q[i * 8 + 2], q[i * 8 + 3]);
            unpack2(u.z, q[i * 8 + 4], q[i * 8 + 5]);
            unpack2(u.w, q[i * 8 + 6], q[i * 8 + 7]);
        }
    }
    __shared__ float Ks[32][HEAD_DIM];
    __shared__ float Vs[32][HEAD_DIM];
    float o[HEAD_DIM];
#pragma unroll
    for (int d = 0; d < HEAD_DIM; ++d) o[d] = 0.f;
    float m = -1e30f, l = 0.f;
    const int kbase = b * SEQ;
    const int lj = tid >> 3;
    const int ld = (tid & 7) * 8;

    for (int kc = 0; kc < SEQ; kc += 32) {
        {
            size_t off = (size_t)(kbase + kc + lj) * 256 + head * HEAD_DIM + ld;
            uint4 uk = *(const uint4*)(kb + off);
            uint4 uv = *(const uint4*)(vb + off);
            unpack2(uk.x, Ks[lj][ld + 0], Ks[lj][ld + 1]);
            unpack2(uk.y, Ks[lj][ld + 2], Ks[lj][ld + 3]);
            unpack2(uk.z, Ks[lj][ld + 4], Ks[lj][ld + 5]);
            unpack2(uk.w, Ks[lj][ld + 6], Ks[lj][ld + 7]);
            unpack2(uv.x, Vs[lj][ld + 0], Vs[lj][ld + 1]);
            unpack2(uv.y, Vs[lj][ld + 2], Vs[lj][ld + 3]);
            unpack2(uv.z, Vs[lj][ld + 4], Vs[lj][ld + 5]);
            unpack2(uv.w, Vs[lj][ld + 6], Vs[lj][ld + 7]);
        }
        __syncthreads();

        float s[32];
#pragma unroll
        for (int j = 0; j < 32; ++j) s[j] = 0.f;
#pragma unroll
        for (int d = 0; d < HEAD_DIM; d += 4) {
#pragma unroll
            for (int j = 0; j < 32; ++j) {
                const float4 kv = *(const float4*)&Ks[j][d];
                s[j] = fmaf(q[d], kv.x,
                       fmaf(q[d + 1], kv.y,
                       fmaf(q[d + 2], kv.z,
                       fmaf(q[d + 3], kv.w, s[j]))));
            }
        }
        float cmax = -1e30f;
#pragma unroll
        for (int j = 0; j < 32; ++j) { s[j] *= 0.125f; cmax = fmaxf(cmax, s[j]); }
        float mnew = fmaxf(m, cmax);
        float corr = __expf(m - mnew);
        l *= corr;
#pragma unroll
        for (int d = 0; d < HEAD_DIM; ++d) o[d] *= corr;
#pragma unroll
        for (int j = 0; j < 32; ++j) {
            float p = __expf(s[j] - mnew);
            l += p;
#pragma unroll
            for (int d = 0; d < HEAD_DIM; d += 4) {
                const float4 vv = *(const float4*)&Vs[j][d];
                o[d]     = fmaf(p, vv.x, o[d]);
                o[d + 1] = fmaf(p, vv.y, o[d + 1]);
                o[d + 2] = fmaf(p, vv.z, o[d + 2]);
                o[d + 3] = fmaf(p, vv.w, o[d + 3]);
            }
        }
        m = mnew;
        __syncthreads();
    }
    float inv = 1.f / l;
    bf16* op = ctx + (size_t)q_node * 256 + head * HEAD_DIM;
#pragma unroll
    for (int d = 0; d < HEAD_DIM; d += 4) {
        __align__(8) bf16 tmp[4];
        tmp[0] = __float2bfloat16(o[d] * inv);
        tmp[1] = __float2bfloat16(o[d + 1] * inv);
        tmp[2] = __float2bfloat16(o[d + 2] * inv);
        tmp[3] = __float2bfloat16(o[d + 3] * inv);
        *(uint2*)(op + d) = *(uint2*)tmp;
    }
}

// ---------------- residual + LayerNorm (+optional ReLU); one wave per node ----------------
__global__ void k_ln(const float* __restrict__ conv, const bf16* __restrict__ proj,
                     const float* __restrict__ lg, const float* __restrict__ lb,
                     bf16* __restrict__ h, int relu) {
    int gt = blockIdx.x * blockDim.x + threadIdx.x;
    int node = gt >> 6;
    int lane = gt & 63;
    size_t base = (size_t)node * 256 + lane * 4;
    const float4 a = *(const float4*)(conv + base);
    uint2 up = *(const uint2*)(proj + base);
    float p0, p1, p2, p3;
    unpack2(up.x, p0, p1);
    unpack2(up.y, p2, p3);
    float y0 = a.x + p0, y1 = a.y + p1, y2 = a.z + p2, y3 = a.w + p3;
    float sum = y0 + y1 + y2 + y3;
#pragma unroll
    for (int off = 32; off > 0; off >>= 1) sum += __shfl_xor(sum, off, 64);
    float mu = sum * (1.0f / 256.0f);
    float d0 = y0 - mu, d1 = y1 - mu, d2 = y2 - mu, d3 = y3 - mu;
    float vs = d0 * d0 + d1 * d1 + d2 * d2 + d3 * d3;
#pragma unroll
    for (int off = 32; off > 0; off >>= 1) vs += __shfl_xor(vs, off, 64);
    float r = rsqrtf(vs * (1.0f / 256.0f) + EPS_LN);
    int c = lane * 4;
    float o0 = fmaf(d0 * r, lg[c + 0], lb[c + 0]);
    float o1 = fmaf(d1 * r, lg[c + 1], lb[c + 1]);
    float o2 = fmaf(d2 * r, lg[c + 2], lb[c + 2]);
    float o3 = fmaf(d3 * r, lg[c + 3], lb[c + 3]);
    if (relu) {
        o0 = fmaxf(o0, 0.f); o1 = fmaxf(o1, 0.f); o2 = fmaxf(o2, 0.f); o3 = fmaxf(o3, 0.f);
    }
    __align__(8) bf16 tmp[4];
    tmp[0] = __float2bfloat16(o0);
    tmp[1] = __float2bfloat16(o1);
    tmp[2] = __float2bfloat16(o2);
    tmp[3] = __float2bfloat16(o3);
    *(uint2*)(h + base) = *(uint2*)tmp;
}

// ---------------- final: h (bf16 -> fp32) + scores; one wave per node ----------------
__global__ void k_out(const bf16* __restrict__ h, const float* __restrict__ sw,
                      const float* __restrict__ sb, float* __restrict__ out) {
    int gt = blockIdx.x * blockDim.x + threadIdx.x;
    int node = gt >> 6;
    int lane = gt & 63;
    size_t base = (size_t)node * 256 + lane * 4;
    uint2 uh = *(const uint2*)(h + base);
    float v0, v1, v2, v3;
    unpack2(uh.x, v0, v1);
    unpack2(uh.y, v2, v3);
    *(float4*)(out + base) = make_float4(v0, v1, v2, v3);
    int c = lane * 4;
    float part = v0 * sw[c + 0] + v1 * sw[c + 1] + v2 * sw[c + 2] + v3 * sw[c + 3];
#pragma unroll
    for (int off = 32; off > 0; off >>= 1) part += __shfl_xor(part, off, 64);
    if (lane == 0)
        out[(size_t)N_NODES * 256 + node] = part + sb[0];
}

extern "C" void kernel_launch(void* const* d_in, const int* in_sizes, int n_in,
                              void* d_out, int out_size, void* d_ws, size_t ws_size,
                              hipStream_t stream) {
    // workspace budget: conv fp32 (32 MiB) + q/k/v/t bf16 (16 MiB each) = 96 MiB exactly.
    if (ws_size < (size_t)100663296) return;  // diagnostic guard (known satisfied from R3)

    const float* x     = (const float*)d_in[0];
    const int*   esrc  = (const int*)d_in[1];
    const int*   edst  = (const int*)d_in[2];
    const float* eattr = (const float*)d_in[3];

    float* conv = (float*)d_ws;
    bf16*  qb   = (bf16*)((char*)d_ws + NH * 4);
    bf16*  kb   = qb + NH;
    bf16*  vb   = kb + NH;
    bf16*  tb   = vb + NH;
    bf16*  hb   = qb;   // h overlays dead q-region between layers
    bf16*  pjb  = kb;   // proj overlays dead k-region

    // weight scratch lives in d_out (fp32 out buffer, 33.7 MB; fully overwritten by k_out)
    float* scr = (float*)d_out;
    const size_t LSTRIDE = 262656;  // 4*65536 (W) + 2*256 (bn), in floats

    for (int L = 0; L < 2; ++L) {
        int bi = 5 + L * 11;
        float* base = scr + (size_t)L * LSTRIDE;
        float* Wq = base;
        float* Wk = Wq + 65536;
        float* Wv = Wk + 65536;
        float* Wo = Wv + 65536;
        float* bns = Wo + 65536;
        float* bnt = bns + 256;
        const float* iw = (const float*)d_in[bi + 5];
        k_tr<<<256, 256, 0, stream>>>(Wq, iw);
        k_tr<<<256, 256, 0, stream>>>(Wk, iw + 65536);
        k_tr<<<256, 256, 0, stream>>>(Wv, iw + 131072);
        k_tr<<<256, 256, 0, stream>>>(Wo, (const float*)d_in[bi + 7]);
        k_bnprep<<<1, 256, 0, stream>>>(bns, bnt, (const float*)d_in[bi + 1],
                                        (const float*)d_in[bi + 2], (const float*)d_in[bi + 3],
                                        (const float*)d_in[bi + 4]);
    }

    for (int L = 0; L < 2; ++L) {
        int bi = 5 + L * 11;
        float* base = scr + (size_t)L * LSTRIDE;
        float* Wq = base;
        float* Wk = Wq + 65536;
        float* Wv = Wk + 65536;
        float* Wo = Wv + 65536;
        float* bns = Wo + 65536;
        float* bnt = bns + 256;
        const float* cw = (const float*)d_in[bi + 0];   // (256,256) row-major: W[k][n] direct
        const float* ib = (const float*)d_in[bi + 6];   // 768 = [q|k|v] biases
        const float* ob = (const float*)d_in[bi + 8];

        // t = (x or h) @ conv_w
        if (L == 0)
            k_gemm<float, float><<<dim3(512, 4), 256, 0, stream>>>(x, cw, nullptr, tb);
        else
            k_gemm<bf16, float><<<dim3(512, 4), 256, 0, stream>>>(hb, cw, nullptr, tb);
        // conv = segment_sum(edge_attr * t[src] -> dst)
        (void)hipMemsetAsync(conv, 0, NH * 4, stream);
        k_scatter<<<E_EDGES / 4, 256, 0, stream>>>(tb, esrc, edst, eattr, conv);
        // BN (eval, folded) in place
        k_bn<<<8192, 256, 0, stream>>>(conv, bns, bnt);
        // q/k/v = conv @ Wq/k/v + bias
        k_gemm<float, float><<<dim3(512, 4), 256, 0, stream>>>(conv, Wq, ib, qb);
        k_gemm<float, float><<<dim3(512, 4), 256, 0, stream>>>(conv, Wk, ib + 256, kb);
        k_gemm<float, float><<<dim3(512, 4), 256, 0, stream>>>(conv, Wv, ib + 512, vb);
        // attention context -> t
        k_attn<<<512, 256, 0, stream>>>(qb, kb, vb, tb);
        // proj = ctx @ Wo + ob  (into dead k-region)
        k_gemm<bf16, float><<<dim3(512, 4), 256, 0, stream>>>(tb, Wo, ob, pjb);
        // h = LN(conv + proj) (+ReLU on layer 0), into dead q-region
        k_ln<<<8192, 256, 0, stream>>>(conv, pjb, (const float*)d_in[bi + 9],
                                       (const float*)d_in[bi + 10], hb, L == 0 ? 1 : 0);
    }

    k_out<<<8192, 256, 0, stream>>>(hb, (const float*)d_in[27], (const float*)d_in[28],
                                    (float*)d_out);
}

// Round 5
// 1758.759 us; speedup vs baseline: 2.8476x; 2.8476x over previous
//
#include <hip/hip_runtime.h>
#include <hip/hip_bf16.h>
#include <math.h>

#define N_NODES 32768
#define E_EDGES 524288
#define NHID    256
#define HEAD_DIM 64
#define SEQ     512
#define EPS_LN  1e-5f

typedef __hip_bfloat16 bf16;
static const size_t NH = (size_t)N_NODES * NHID;  // 8,388,608

__device__ __forceinline__ void unpack2(unsigned int u, float& lo, float& hi) {
    union { float f; unsigned int i; } a, b;
    a.i = u << 16; b.i = u & 0xffff0000u;
    lo = a.f; hi = b.f;
}

__device__ __forceinline__ float4 load4f(const float* p) { return *(const float4*)p; }
__device__ __forceinline__ float4 load4f(const bf16* p) {
    uint2 u = *(const uint2*)p;
    float4 r;
    unpack2(u.x, r.x, r.y);
    unpack2(u.y, r.z, r.w);
    return r;
}

// ---------------- transpose 256x256 fp32: dst[c][r] = src[r][c] ----------------
__global__ void k_tr(float* __restrict__ dst, const float* __restrict__ src) {
    int r = blockIdx.x, c = threadIdx.x;
    dst[(size_t)c * 256 + r] = src[(size_t)r * 256 + c];
}

// fold BN eval-mode into scale/shift: s = g*rsqrt(v+eps), t = b - m*s
__global__ void k_bnprep(float* __restrict__ s, float* __restrict__ t,
                         const float* g, const float* b, const float* m, const float* v) {
    int c = threadIdx.x;
    float sv = g[c] * rsqrtf(v[c] + EPS_LN);
    s[c] = sv;
    t[c] = b[c] - m[c] * sv;
}

// ---------------- CSR build: histogram -> scan -> fill ----------------
__global__ void k_hist(const int* __restrict__ edst, int* __restrict__ counts) {
    int e = blockIdx.x * 256 + threadIdx.x;
    atomicAdd(&counts[edst[e]], 1);
}

// single block, 256 threads, 128 counts each: exclusive scan of 32768 -> offsets[0..32768]
__global__ __launch_bounds__(256) void k_scan(const int* __restrict__ counts,
                                              int* __restrict__ offsets,
                                              int* __restrict__ cursor) {
    __shared__ int sums[256];
    const int tid = threadIdx.x;
    const int base = tid * 128;
    int s = 0;
    for (int i = 0; i < 128; ++i) s += counts[base + i];
    sums[tid] = s;
    __syncthreads();
    for (int off = 1; off < 256; off <<= 1) {
        int v = (tid >= off) ? sums[tid - off] : 0;
        __syncthreads();
        sums[tid] += v;
        __syncthreads();
    }
    int run = (tid == 0) ? 0 : sums[tid - 1];
    for (int i = 0; i < 128; ++i) {
        int c = counts[base + i];
        offsets[base + i] = run;
        cursor[base + i] = run;
        run += c;
    }
    if (tid == 255) offsets[32768] = run;
}

__global__ void k_fill(const int* __restrict__ esrc, const int* __restrict__ edst,
                       const float* __restrict__ eattr, int* __restrict__ cursor,
                       int* __restrict__ srcp, float* __restrict__ attrp) {
    int e = blockIdx.x * 256 + threadIdx.x;
    int d = edst[e];
    int slot = atomicAdd(&cursor[d], 1);
    srcp[slot] = esrc[e];
    attrp[slot] = eattr[e];
}

// ---------------- conv gather + fused BN: one wave per dst node ----------------
// conv[n] = BN( sum_{e in CSR[n]} attr[e] * t[src[e]] )
__global__ __launch_bounds__(256) void k_gather(const bf16* __restrict__ t,
                                                const int* __restrict__ offsets,
                                                const int* __restrict__ srcp,
                                                const float* __restrict__ attrp,
                                                const float* __restrict__ bns,
                                                const float* __restrict__ bnt,
                                                float* __restrict__ conv) {
    const int node = (blockIdx.x * 256 + threadIdx.x) >> 6;
    const int lane = threadIdx.x & 63;
    const int start = offsets[node];
    const int end = offsets[node + 1];
    float a0 = 0.f, a1 = 0.f, a2 = 0.f, a3 = 0.f;
    for (int c0 = start; c0 < end; c0 += 64) {
        const int n = min(64, end - c0);
        int sidx = 0;
        float sa = 0.f;
        if (lane < n) {
            sidx = srcp[c0 + lane];   // coalesced per-lane preload
            sa = attrp[c0 + lane];
        }
        for (int j = 0; j < n; ++j) {
            const int s = __shfl(sidx, j, 64);
            const float a = __shfl(sa, j, 64);
            uint2 u = *(const uint2*)(t + (size_t)s * 256 + lane * 4);
            float v0, v1, v2, v3;
            unpack2(u.x, v0, v1);
            unpack2(u.y, v2, v3);
            a0 = fmaf(a, v0, a0);
            a1 = fmaf(a, v1, a1);
            a2 = fmaf(a, v2, a2);
            a3 = fmaf(a, v3, a3);
        }
    }
    const int c = lane * 4;
    const float4 sv = *(const float4*)(bns + c);
    const float4 tv = *(const float4*)(bnt + c);
    float4 o;
    o.x = fmaf(a0, sv.x, tv.x);
    o.y = fmaf(a1, sv.y, tv.y);
    o.z = fmaf(a2, sv.z, tv.z);
    o.w = fmaf(a3, sv.w, tv.w);
    *(float4*)(conv + (size_t)node * 256 + c) = o;
}

// ---------------- GEMM: C[32768 x 256] = A[32768 x 256] * W[256 x 256] (+bias), bf16 out ----
template <typename AT, typename WT>
__global__ __launch_bounds__(256) void k_gemm(const AT* __restrict__ A,
                                              const WT* __restrict__ W,
                                              const float* __restrict__ bias,
                                              bf16* __restrict__ C) {
    __shared__ float As[16][68];
    __shared__ float Ws[16][68];
    const int tid = threadIdx.x;
    const int bm = blockIdx.x * 64;
    const int bn = blockIdx.y * 64;
    const int tm = (tid & 15) << 2;
    const int tn = (tid >> 4) << 2;
    const int am = tid >> 2;          // 0..63
    const int ak = (tid & 3) << 2;    // 0,4,8,12
    const int wk = tid >> 4;          // 0..15
    const int wn = (tid & 15) << 2;   // 0..60
    float acc[4][4] = {};

    for (int k0 = 0; k0 < 256; k0 += 16) {
        const float4 av = load4f(A + (size_t)(bm + am) * 256 + k0 + ak);
        const float4 wv = load4f(W + (size_t)(k0 + wk) * 256 + bn + wn);
        As[ak + 0][am] = av.x;
        As[ak + 1][am] = av.y;
        As[ak + 2][am] = av.z;
        As[ak + 3][am] = av.w;
        *(float4*)&Ws[wk][wn] = wv;
        __syncthreads();
#pragma unroll
        for (int k = 0; k < 16; ++k) {
            const float4 a = *(const float4*)&As[k][tm];
            const float4 b = *(const float4*)&Ws[k][tn];
            acc[0][0] = fmaf(a.x, b.x, acc[0][0]);
            acc[0][1] = fmaf(a.x, b.y, acc[0][1]);
            acc[0][2] = fmaf(a.x, b.z, acc[0][2]);
            acc[0][3] = fmaf(a.x, b.w, acc[0][3]);
            acc[1][0] = fmaf(a.y, b.x, acc[1][0]);
            acc[1][1] = fmaf(a.y, b.y, acc[1][1]);
            acc[1][2] = fmaf(a.y, b.z, acc[1][2]);
            acc[1][3] = fmaf(a.y, b.w, acc[1][3]);
            acc[2][0] = fmaf(a.z, b.x, acc[2][0]);
            acc[2][1] = fmaf(a.z, b.y, acc[2][1]);
            acc[2][2] = fmaf(a.z, b.z, acc[2][2]);
            acc[2][3] = fmaf(a.z, b.w, acc[2][3]);
            acc[3][0] = fmaf(a.w, b.x, acc[3][0]);
            acc[3][1] = fmaf(a.w, b.y, acc[3][1]);
            acc[3][2] = fmaf(a.w, b.z, acc[3][2]);
            acc[3][3] = fmaf(a.w, b.w, acc[3][3]);
        }
        __syncthreads();
    }
    float4 bv = make_float4(0.f, 0.f, 0.f, 0.f);
    if (bias) bv = load4f(bias + bn + tn);
#pragma unroll
    for (int i = 0; i < 4; ++i) {
        __align__(8) bf16 tmp[4];
        tmp[0] = __float2bfloat16(acc[i][0] + bv.x);
        tmp[1] = __float2bfloat16(acc[i][1] + bv.y);
        tmp[2] = __float2bfloat16(acc[i][2] + bv.z);
        tmp[3] = __float2bfloat16(acc[i][3] + bv.w);
        *(uint2*)&C[(size_t)(bm + tm + i) * 256 + bn + tn] = *(uint2*)tmp;
    }
}

// ---------------- attention: block = (graph, head, half); thread = 1 query ----------------
__global__ __launch_bounds__(256, 1) void k_attn(const bf16* __restrict__ qb,
                                                 const bf16* __restrict__ kb,
                                                 const bf16* __restrict__ vb,
                                                 bf16* __restrict__ ctx) {
    const int blk = blockIdx.x;
    const int half = blk & 1;
    const int head = (blk >> 1) & 3;
    const int b = blk >> 3;
    const int tid = threadIdx.x;
    const int q_node = b * SEQ + half * 256 + tid;

    float q[HEAD_DIM];
    {
        const bf16* qp = qb + (size_t)q_node * 256 + head * HEAD_DIM;
#pragma unroll
        for (int i = 0; i < 8; ++i) {
            uint4 u = *(const uint4*)(qp + i * 8);
            unpack2(u.x, q[i * 8 + 0], q[i * 8 + 1]);
            unpack2(u.y, q[i * 8 + 2], q[i * 8 + 3]);
            unpack2(u.z, q[i * 8 + 4], q[i * 8 + 5]);
            unpack2(u.w, q[i * 8 + 6], q[i * 8 + 7]);
        }
    }
    __shared__ float Ks[32][HEAD_DIM];
    __shared__ float Vs[32][HEAD_DIM];
    float o[HEAD_DIM];
#pragma unroll
    for (int d = 0; d < HEAD_DIM; ++d) o[d] = 0.f;
    float m = -1e30f, l = 0.f;
    const int kbase = b * SEQ;
    const int lj = tid >> 3;
    const int ld = (tid & 7) * 8;

    for (int kc = 0; kc < SEQ; kc += 32) {
        {
            size_t off = (size_t)(kbase + kc + lj) * 256 + head * HEAD_DIM + ld;
            uint4 uk = *(const uint4*)(kb + off);
            uint4 uv = *(const uint4*)(vb + off);
            unpack2(uk.x, Ks[lj][ld + 0], Ks[lj][ld + 1]);
            unpack2(uk.y, Ks[lj][ld + 2], Ks[lj][ld + 3]);
            unpack2(uk.z, Ks[lj][ld + 4], Ks[lj][ld + 5]);
            unpack2(uk.w, Ks[lj][ld + 6], Ks[lj][ld + 7]);
            unpack2(uv.x, Vs[lj][ld + 0], Vs[lj][ld + 1]);
            unpack2(uv.y, Vs[lj][ld + 2], Vs[lj][ld + 3]);
            unpack2(uv.z, Vs[lj][ld + 4], Vs[lj][ld + 5]);
            unpack2(uv.w, Vs[lj][ld + 6], Vs[lj][ld + 7]);
        }
        __syncthreads();

        float s[32];
#pragma unroll
        for (int j = 0; j < 32; ++j) s[j] = 0.f;
#pragma unroll
        for (int d = 0; d < HEAD_DIM; d += 4) {
#pragma unroll
            for (int j = 0; j < 32; ++j) {
                const float4 kv = *(const float4*)&Ks[j][d];
                s[j] = fmaf(q[d], kv.x,
                       fmaf(q[d + 1], kv.y,
                       fmaf(q[d + 2], kv.z,
                       fmaf(q[d + 3], kv.w, s[j]))));
            }
        }
        float cmax = -1e30f;
#pragma unroll
        for (int j = 0; j < 32; ++j) { s[j] *= 0.125f; cmax = fmaxf(cmax, s[j]); }
        float mnew = fmaxf(m, cmax);
        float corr = __expf(m - mnew);
        l *= corr;
#pragma unroll
        for (int d = 0; d < HEAD_DIM; ++d) o[d] *= corr;
#pragma unroll
        for (int j = 0; j < 32; ++j) {
            float p = __expf(s[j] - mnew);
            l += p;
#pragma unroll
            for (int d = 0; d < HEAD_DIM; d += 4) {
                const float4 vv = *(const float4*)&Vs[j][d];
                o[d]     = fmaf(p, vv.x, o[d]);
                o[d + 1] = fmaf(p, vv.y, o[d + 1]);
                o[d + 2] = fmaf(p, vv.z, o[d + 2]);
                o[d + 3] = fmaf(p, vv.w, o[d + 3]);
            }
        }
        m = mnew;
        __syncthreads();
    }
    float inv = 1.f / l;
    bf16* op = ctx + (size_t)q_node * 256 + head * HEAD_DIM;
#pragma unroll
    for (int d = 0; d < HEAD_DIM; d += 4) {
        __align__(8) bf16 tmp[4];
        tmp[0] = __float2bfloat16(o[d] * inv);
        tmp[1] = __float2bfloat16(o[d + 1] * inv);
        tmp[2] = __float2bfloat16(o[d + 2] * inv);
        tmp[3] = __float2bfloat16(o[d + 3] * inv);
        *(uint2*)(op + d) = *(uint2*)tmp;
    }
}

// ---------------- residual + LayerNorm (+optional ReLU); one wave per node ----------------
__global__ void k_ln(const float* __restrict__ conv, const bf16* __restrict__ proj,
                     const float* __restrict__ lg, const float* __restrict__ lb,
                     bf16* __restrict__ h, int relu) {
    int gt = blockIdx.x * blockDim.x + threadIdx.x;
    int node = gt >> 6;
    int lane = gt & 63;
    size_t base = (size_t)node * 256 + lane * 4;
    const float4 a = *(const float4*)(conv + base);
    uint2 up = *(const uint2*)(proj + base);
    float p0, p1, p2, p3;
    unpack2(up.x, p0, p1);
    unpack2(up.y, p2, p3);
    float y0 = a.x + p0, y1 = a.y + p1, y2 = a.z + p2, y3 = a.w + p3;
    float sum = y0 + y1 + y2 + y3;
#pragma unroll
    for (int off = 32; off > 0; off >>= 1) sum += __shfl_xor(sum, off, 64);
    float mu = sum * (1.0f / 256.0f);
    float d0 = y0 - mu, d1 = y1 - mu, d2 = y2 - mu, d3 = y3 - mu;
    float vs = d0 * d0 + d1 * d1 + d2 * d2 + d3 * d3;
#pragma unroll
    for (int off = 32; off > 0; off >>= 1) vs += __shfl_xor(vs, off, 64);
    float r = rsqrtf(vs * (1.0f / 256.0f) + EPS_LN);
    int c = lane * 4;
    float o0 = fmaf(d0 * r, lg[c + 0], lb[c + 0]);
    float o1 = fmaf(d1 * r, lg[c + 1], lb[c + 1]);
    float o2 = fmaf(d2 * r, lg[c + 2], lb[c + 2]);
    float o3 = fmaf(d3 * r, lg[c + 3], lb[c + 3]);
    if (relu) {
        o0 = fmaxf(o0, 0.f); o1 = fmaxf(o1, 0.f); o2 = fmaxf(o2, 0.f); o3 = fmaxf(o3, 0.f);
    }
    __align__(8) bf16 tmp[4];
    tmp[0] = __float2bfloat16(o0);
    tmp[1] = __float2bfloat16(o1);
    tmp[2] = __float2bfloat16(o2);
    tmp[3] = __float2bfloat16(o3);
    *(uint2*)(h + base) = *(uint2*)tmp;
}

// ---------------- final: h (bf16 -> fp32) + scores; one wave per node ----------------
__global__ void k_out(const bf16* __restrict__ h, const float* __restrict__ sw,
                      const float* __restrict__ sb, float* __restrict__ out) {
    int gt = blockIdx.x * blockDim.x + threadIdx.x;
    int node = gt >> 6;
    int lane = gt & 63;
    size_t base = (size_t)node * 256 + lane * 4;
    uint2 uh = *(const uint2*)(h + base);
    float v0, v1, v2, v3;
    unpack2(uh.x, v0, v1);
    unpack2(uh.y, v2, v3);
    *(float4*)(out + base) = make_float4(v0, v1, v2, v3);
    int c = lane * 4;
    float part = v0 * sw[c + 0] + v1 * sw[c + 1] + v2 * sw[c + 2] + v3 * sw[c + 3];
#pragma unroll
    for (int off = 32; off > 0; off >>= 1) part += __shfl_xor(part, off, 64);
    if (lane == 0)
        out[(size_t)N_NODES * 256 + node] = part + sb[0];
}

extern "C" void kernel_launch(void* const* d_in, const int* in_sizes, int n_in,
                              void* d_out, int out_size, void* d_ws, size_t ws_size,
                              hipStream_t stream) {
    // workspace budget: conv fp32 (32 MiB) + q/k/v/t bf16 (16 MiB each) = 96 MiB exactly.
    if (ws_size < (size_t)100663296) return;

    const float* x     = (const float*)d_in[0];
    const int*   esrc  = (const int*)d_in[1];
    const int*   edst  = (const int*)d_in[2];
    const float* eattr = (const float*)d_in[3];

    float* conv = (float*)d_ws;
    bf16*  qb   = (bf16*)((char*)d_ws + NH * 4);
    bf16*  kb   = qb + NH;
    bf16*  vb   = kb + NH;
    bf16*  tb   = vb + NH;
    bf16*  hb   = qb;   // h overlays dead q-region between layers
    bf16*  pjb  = kb;   // proj overlays dead k-region

    // scratch inside d_out (fp32 out buffer, 33.7 MB; fully overwritten by k_out at the end):
    //   [0 .. 525312)                weights (2 layers x 262656 floats)
    //   then counts / offsets / cursor / srcp / attrp  (CSR, ~4.6 MB)
    float* scr = (float*)d_out;
    const size_t LSTRIDE = 262656;  // 4*65536 (W) + 2*256 (bn), in floats
    int*   counts  = (int*)(scr + 2 * LSTRIDE);
    int*   offsets = counts + 32768;          // 32769 entries
    int*   cursor  = offsets + 32769;
    int*   srcp    = cursor + 32768;
    float* attrp   = (float*)(srcp + E_EDGES);

    // --- CSR build (edges shared by both layers) ---
    (void)hipMemsetAsync(counts, 0, 32768 * sizeof(int), stream);
    k_hist<<<E_EDGES / 256, 256, 0, stream>>>(edst, counts);
    k_scan<<<1, 256, 0, stream>>>(counts, offsets, cursor);
    k_fill<<<E_EDGES / 256, 256, 0, stream>>>(esrc, edst, eattr, cursor, srcp, attrp);

    // --- weight staging ---
    for (int L = 0; L < 2; ++L) {
        int bi = 5 + L * 11;
        float* base = scr + (size_t)L * LSTRIDE;
        float* Wq = base;
        float* Wk = Wq + 65536;
        float* Wv = Wk + 65536;
        float* Wo = Wv + 65536;
        float* bns = Wo + 65536;
        float* bnt = bns + 256;
        const float* iw = (const float*)d_in[bi + 5];
        k_tr<<<256, 256, 0, stream>>>(Wq, iw);
        k_tr<<<256, 256, 0, stream>>>(Wk, iw + 65536);
        k_tr<<<256, 256, 0, stream>>>(Wv, iw + 131072);
        k_tr<<<256, 256, 0, stream>>>(Wo, (const float*)d_in[bi + 7]);
        k_bnprep<<<1, 256, 0, stream>>>(bns, bnt, (const float*)d_in[bi + 1],
                                        (const float*)d_in[bi + 2], (const float*)d_in[bi + 3],
                                        (const float*)d_in[bi + 4]);
    }

    for (int L = 0; L < 2; ++L) {
        int bi = 5 + L * 11;
        float* base = scr + (size_t)L * LSTRIDE;
        float* Wq = base;
        float* Wk = Wq + 65536;
        float* Wv = Wk + 65536;
        float* Wo = Wv + 65536;
        float* bns = Wo + 65536;
        float* bnt = bns + 256;
        const float* cw = (const float*)d_in[bi + 0];   // (256,256) row-major: W[k][n] direct
        const float* ib = (const float*)d_in[bi + 6];   // 768 = [q|k|v] biases
        const float* ob = (const float*)d_in[bi + 8];

        // t = (x or h) @ conv_w
        if (L == 0)
            k_gemm<float, float><<<dim3(512, 4), 256, 0, stream>>>(x, cw, nullptr, tb);
        else
            k_gemm<bf16, float><<<dim3(512, 4), 256, 0, stream>>>(hb, cw, nullptr, tb);
        // conv[n] = BN( sum_{e: dst=n} attr_e * t[src_e] )  -- CSR gather, no atomics
        k_gather<<<8192, 256, 0, stream>>>(tb, offsets, srcp, attrp, bns, bnt, conv);
        // q/k/v = conv @ Wq/k/v + bias
        k_gemm<float, float><<<dim3(512, 4), 256, 0, stream>>>(conv, Wq, ib, qb);
        k_gemm<float, float><<<dim3(512, 4), 256, 0, stream>>>(conv, Wk, ib + 256, kb);
        k_gemm<float, float><<<dim3(512, 4), 256, 0, stream>>>(conv, Wv, ib + 512, vb);
        // attention context -> t
        k_attn<<<512, 256, 0, stream>>>(qb, kb, vb, tb);
        // proj = ctx @ Wo + ob  (into dead k-region)
        k_gemm<bf16, float><<<dim3(512, 4), 256, 0, stream>>>(tb, Wo, ob, pjb);
        // h = LN(conv + proj) (+ReLU on layer 0), into dead q-region
        k_ln<<<8192, 256, 0, stream>>>(conv, pjb, (const float*)d_in[bi + 9],
                                       (const float*)d_in[bi + 10], hb, L == 0 ? 1 : 0);
    }

    k_out<<<8192, 256, 0, stream>>>(hb, (const float*)d_in[27], (const float*)d_in[28],
                                    (float*)d_out);
}

// Round 6
// 1318.898 us; speedup vs baseline: 3.7973x; 1.3335x over previous
//
#include <hip/hip_runtime.h>
#include <hip/hip_bf16.h>
#include <math.h>

#define N_NODES 32768
#define E_EDGES 524288
#define NHID    256
#define HEAD_DIM 64
#define SEQ     512
#define EPS_LN  1e-5f

typedef __hip_bfloat16 bf16;
typedef __attribute__((ext_vector_type(8))) short short8;   // 8 bf16 (4 VGPRs)
typedef __attribute__((ext_vector_type(4))) float floatx4;  // MFMA accumulator
static const size_t NH = (size_t)N_NODES * NHID;  // 8,388,608

__device__ __forceinline__ void unpack2(unsigned int u, float& lo, float& hi) {
    union { float f; unsigned int i; } a, b;
    a.i = u << 16; b.i = u & 0xffff0000u;
    lo = a.f; hi = b.f;
}

// ---------------- staging: fp32 -> bf16 casts ----------------
__global__ void k_cvtb4(bf16* __restrict__ dst, const float* __restrict__ src) {
    size_t i = (size_t)(blockIdx.x * 256 + threadIdx.x) * 4;
    const float4 v = *(const float4*)(src + i);
    __align__(8) bf16 tmp[4];
    tmp[0] = __float2bfloat16(v.x);
    tmp[1] = __float2bfloat16(v.y);
    tmp[2] = __float2bfloat16(v.z);
    tmp[3] = __float2bfloat16(v.w);
    *(uint2*)(dst + i) = *(uint2*)tmp;
}

// transpose+cast 256x256: dst[n*256+k] = bf16(src[k*256+n])
__global__ void k_trb(bf16* __restrict__ dst, const float* __restrict__ src) {
    int k = blockIdx.x, n = threadIdx.x;
    dst[(size_t)n * 256 + k] = __float2bfloat16(src[(size_t)k * 256 + n]);
}

// fold BN eval-mode into scale/shift: s = g*rsqrt(v+eps), t = b - m*s
__global__ void k_bnprep(float* __restrict__ s, float* __restrict__ t,
                         const float* g, const float* b, const float* m, const float* v) {
    int c = threadIdx.x;
    float sv = g[c] * rsqrtf(v[c] + EPS_LN);
    s[c] = sv;
    t[c] = b[c] - m[c] * sv;
}

// ---------------- CSR build: histogram -> scan -> fill ----------------
__global__ void k_hist(const int* __restrict__ edst, int* __restrict__ counts) {
    int e = blockIdx.x * 256 + threadIdx.x;
    atomicAdd(&counts[edst[e]], 1);
}

__global__ __launch_bounds__(256) void k_scan(const int* __restrict__ counts,
                                              int* __restrict__ offsets,
                                              int* __restrict__ cursor) {
    __shared__ int sums[256];
    const int tid = threadIdx.x;
    const int base = tid * 128;
    int s = 0;
    for (int i = 0; i < 128; ++i) s += counts[base + i];
    sums[tid] = s;
    __syncthreads();
    for (int off = 1; off < 256; off <<= 1) {
        int v = (tid >= off) ? sums[tid - off] : 0;
        __syncthreads();
        sums[tid] += v;
        __syncthreads();
    }
    int run = (tid == 0) ? 0 : sums[tid - 1];
    for (int i = 0; i < 128; ++i) {
        int c = counts[base + i];
        offsets[base + i] = run;
        cursor[base + i] = run;
        run += c;
    }
    if (tid == 255) offsets[32768] = run;
}

__global__ void k_fill(const int* __restrict__ esrc, const int* __restrict__ edst,
                       const float* __restrict__ eattr, int* __restrict__ cursor,
                       int* __restrict__ srcp, float* __restrict__ attrp) {
    int e = blockIdx.x * 256 + threadIdx.x;
    int d = edst[e];
    int slot = atomicAdd(&cursor[d], 1);
    srcp[slot] = esrc[e];
    attrp[slot] = eattr[e];
}

// ---------------- conv gather + fused BN: one wave per dst node; bf16 out ----------------
__global__ __launch_bounds__(256) void k_gather(const bf16* __restrict__ t,
                                                const int* __restrict__ offsets,
                                                const int* __restrict__ srcp,
                                                const float* __restrict__ attrp,
                                                const float* __restrict__ bns,
                                                const float* __restrict__ bnt,
                                                bf16* __restrict__ conv) {
    const int node = (blockIdx.x * 256 + threadIdx.x) >> 6;
    const int lane = threadIdx.x & 63;
    const int start = offsets[node];
    const int end = offsets[node + 1];
    float a0 = 0.f, a1 = 0.f, a2 = 0.f, a3 = 0.f;
    for (int c0 = start; c0 < end; c0 += 64) {
        const int n = min(64, end - c0);
        int sidx = 0;
        float sa = 0.f;
        if (lane < n) {
            sidx = srcp[c0 + lane];
            sa = attrp[c0 + lane];
        }
        for (int j = 0; j < n; ++j) {
            const int s = __shfl(sidx, j, 64);
            const float a = __shfl(sa, j, 64);
            uint2 u = *(const uint2*)(t + (size_t)s * 256 + lane * 4);
            float v0, v1, v2, v3;
            unpack2(u.x, v0, v1);
            unpack2(u.y, v2, v3);
            a0 = fmaf(a, v0, a0);
            a1 = fmaf(a, v1, a1);
            a2 = fmaf(a, v2, a2);
            a3 = fmaf(a, v3, a3);
        }
    }
    const int c = lane * 4;
    const float4 sv = *(const float4*)(bns + c);
    const float4 tv = *(const float4*)(bnt + c);
    __align__(8) bf16 tmp[4];
    tmp[0] = __float2bfloat16(fmaf(a0, sv.x, tv.x));
    tmp[1] = __float2bfloat16(fmaf(a1, sv.y, tv.y));
    tmp[2] = __float2bfloat16(fmaf(a2, sv.z, tv.z));
    tmp[3] = __float2bfloat16(fmaf(a3, sv.w, tv.w));
    *(uint2*)(conv + (size_t)node * 256 + c) = *(uint2*)tmp;
}

// ---------------- MFMA GEMM: C[32768x256] = A[32768x256] @ B, B staged as WT[n][k] bf16 ----
// 128x128 tile, BK=64, 4 waves (2x2), 4x4 acc tiles of 16x16x32 per wave.
__global__ __launch_bounds__(256) void k_gemm(const bf16* __restrict__ A,
                                              const bf16* __restrict__ WT,
                                              const float* __restrict__ bias,
                                              bf16* __restrict__ C) {
    __shared__ short As[128][72];   // pitch 72 shorts = 144 B -> <=2-way bank alias (free)
    __shared__ short Bs[128][72];
    const int tid = threadIdx.x;
    const int bm = blockIdx.x * 128;
    const int bn = blockIdx.y * 128;
    const int wid = tid >> 6;
    const int lane = tid & 63;
    const int wr = (wid >> 1) * 64;
    const int wc = (wid & 1) * 64;
    const int quad = lane >> 4;
    const int l16 = lane & 15;

    floatx4 acc[4][4];
#pragma unroll
    for (int mi = 0; mi < 4; ++mi)
#pragma unroll
        for (int ni = 0; ni < 4; ++ni)
            acc[mi][ni] = (floatx4){0.f, 0.f, 0.f, 0.f};

    const int srow = tid >> 3;       // 0..31 (+32*i)
    const int scol = (tid & 7) * 8;  // 0..56

    for (int k0 = 0; k0 < 256; k0 += 64) {
#pragma unroll
        for (int i = 0; i < 4; ++i) {
            const int row = srow + 32 * i;
            *(uint4*)&As[row][scol] = *(const uint4*)(A + (size_t)(bm + row) * 256 + k0 + scol);
            *(uint4*)&Bs[row][scol] = *(const uint4*)(WT + (size_t)(bn + row) * 256 + k0 + scol);
        }
        __syncthreads();
#pragma unroll
        for (int kk = 0; kk < 2; ++kk) {
            const int kcol = kk * 32 + quad * 8;
            short8 af[4], bfr[4];
#pragma unroll
            for (int mi = 0; mi < 4; ++mi) af[mi] = *(const short8*)&As[wr + mi * 16 + l16][kcol];
#pragma unroll
            for (int ni = 0; ni < 4; ++ni) bfr[ni] = *(const short8*)&Bs[wc + ni * 16 + l16][kcol];
#pragma unroll
            for (int mi = 0; mi < 4; ++mi)
#pragma unroll
                for (int ni = 0; ni < 4; ++ni)
                    acc[mi][ni] = __builtin_amdgcn_mfma_f32_16x16x32_bf16(af[mi], bfr[ni],
                                                                          acc[mi][ni], 0, 0, 0);
        }
        __syncthreads();
    }
    // C/D layout: col = lane&15, row = quad*4 + reg
#pragma unroll
    for (int ni = 0; ni < 4; ++ni) {
        const int gc = bn + wc + ni * 16 + l16;
        const float bv = bias ? bias[gc] : 0.f;
#pragma unroll
        for (int mi = 0; mi < 4; ++mi) {
            const int gr = bm + wr + mi * 16 + quad * 4;
#pragma unroll
            for (int r = 0; r < 4; ++r)
                C[(size_t)(gr + r) * 256 + gc] = __float2bfloat16(acc[mi][ni][r] + bv);
        }
    }
}

// ---------------- attention: block = (graph, head, half); thread = 1 query ----------------
__global__ __launch_bounds__(256, 1) void k_attn(const bf16* __restrict__ qb,
                                                 const bf16* __restrict__ kb,
                                                 const bf16* __restrict__ vb,
                                                 bf16* __restrict__ ctx) {
    const int blk = blockIdx.x;
    const int half = blk & 1;
    const int head = (blk >> 1) & 3;
    const int b = blk >> 3;
    const int tid = threadIdx.x;
    const int q_node = b * SEQ + half * 256 + tid;

    float q[HEAD_DIM];
    {
        const bf16* qp = qb + (size_t)q_node * 256 + head * HEAD_DIM;
#pragma unroll
        for (int i = 0; i < 8; ++i) {
            uint4 u = *(const uint4*)(qp + i * 8);
            unpack2(u.x, q[i * 8 + 0], q[i * 8 + 1]);
            unpack2(u.y, q[i * 8 + 2], q[i * 8 + 3]);
            unpack2(u.z, q[i * 8 + 4], q[i * 8 + 5]);
            unpack2(u.w, q[i * 8 + 6], q[i * 8 + 7]);
        }
    }
    __shared__ float Ks[32][HEAD_DIM];
    __shared__ float Vs[32][HEAD_DIM];
    float o[HEAD_DIM];
#pragma unroll
    for (int d = 0; d < HEAD_DIM; ++d) o[d] = 0.f;
    float m = -1e30f, l = 0.f;
    const int kbase = b * SEQ;
    const int lj = tid >> 3;
    const int ld = (tid & 7) * 8;

    for (int kc = 0; kc < SEQ; kc += 32) {
        {
            size_t off = (size_t)(kbase + kc + lj) * 256 + head * HEAD_DIM + ld;
            uint4 uk = *(const uint4*)(kb + off);
            uint4 uv = *(const uint4*)(vb + off);
            unpack2(uk.x, Ks[lj][ld + 0], Ks[lj][ld + 1]);
            unpack2(uk.y, Ks[lj][ld + 2], Ks[lj][ld + 3]);
            unpack2(uk.z, Ks[lj][ld + 4], Ks[lj][ld + 5]);
            unpack2(uk.w, Ks[lj][ld + 6], Ks[lj][ld + 7]);
            unpack2(uv.x, Vs[lj][ld + 0], Vs[lj][ld + 1]);
            unpack2(uv.y, Vs[lj][ld + 2], Vs[lj][ld + 3]);
            unpack2(uv.z, Vs[lj][ld + 4], Vs[lj][ld + 5]);
            unpack2(uv.w, Vs[lj][ld + 6], Vs[lj][ld + 7]);
        }
        __syncthreads();

        float s[32];
#pragma unroll
        for (int j = 0; j < 32; ++j) s[j] = 0.f;
#pragma unroll
        for (int d = 0; d < HEAD_DIM; d += 4) {
#pragma unroll
            for (int j = 0; j < 32; ++j) {
                const float4 kv = *(const float4*)&Ks[j][d];
                s[j] = fmaf(q[d], kv.x,
                       fmaf(q[d + 1], kv.y,
                       fmaf(q[d + 2], kv.z,
                       fmaf(q[d + 3], kv.w, s[j]))));
            }
        }
        float cmax = -1e30f;
#pragma unroll
        for (int j = 0; j < 32; ++j) { s[j] *= 0.125f; cmax = fmaxf(cmax, s[j]); }
        float mnew = fmaxf(m, cmax);
        float corr = __expf(m - mnew);
        l *= corr;
#pragma unroll
        for (int d = 0; d < HEAD_DIM; ++d) o[d] *= corr;
#pragma unroll
        for (int j = 0; j < 32; ++j) {
            float p = __expf(s[j] - mnew);
            l += p;
#pragma unroll
            for (int d = 0; d < HEAD_DIM; d += 4) {
                const float4 vv = *(const float4*)&Vs[j][d];
                o[d]     = fmaf(p, vv.x, o[d]);
                o[d + 1] = fmaf(p, vv.y, o[d + 1]);
                o[d + 2] = fmaf(p, vv.z, o[d + 2]);
                o[d + 3] = fmaf(p, vv.w, o[d + 3]);
            }
        }
        m = mnew;
        __syncthreads();
    }
    float inv = 1.f / l;
    bf16* op = ctx + (size_t)q_node * 256 + head * HEAD_DIM;
#pragma unroll
    for (int d = 0; d < HEAD_DIM; d += 4) {
        __align__(8) bf16 tmp[4];
        tmp[0] = __float2bfloat16(o[d] * inv);
        tmp[1] = __float2bfloat16(o[d + 1] * inv);
        tmp[2] = __float2bfloat16(o[d + 2] * inv);
        tmp[3] = __float2bfloat16(o[d + 3] * inv);
        *(uint2*)(op + d) = *(uint2*)tmp;
    }
}

// ---------------- residual + LayerNorm (+optional ReLU); one wave per node ----------------
__global__ void k_ln(const bf16* __restrict__ conv, const bf16* __restrict__ proj,
                     const float* __restrict__ lg, const float* __restrict__ lb,
                     bf16* __restrict__ h, int relu) {
    int gt = blockIdx.x * blockDim.x + threadIdx.x;
    int node = gt >> 6;
    int lane = gt & 63;
    size_t base = (size_t)node * 256 + lane * 4;
    uint2 ua = *(const uint2*)(conv + base);
    uint2 up = *(const uint2*)(proj + base);
    float a0, a1, a2, a3, p0, p1, p2, p3;
    unpack2(ua.x, a0, a1);
    unpack2(ua.y, a2, a3);
    unpack2(up.x, p0, p1);
    unpack2(up.y, p2, p3);
    float y0 = a0 + p0, y1 = a1 + p1, y2 = a2 + p2, y3 = a3 + p3;
    float sum = y0 + y1 + y2 + y3;
#pragma unroll
    for (int off = 32; off > 0; off >>= 1) sum += __shfl_xor(sum, off, 64);
    float mu = sum * (1.0f / 256.0f);
    float d0 = y0 - mu, d1 = y1 - mu, d2 = y2 - mu, d3 = y3 - mu;
    float vs = d0 * d0 + d1 * d1 + d2 * d2 + d3 * d3;
#pragma unroll
    for (int off = 32; off > 0; off >>= 1) vs += __shfl_xor(vs, off, 64);
    float r = rsqrtf(vs * (1.0f / 256.0f) + EPS_LN);
    int c = lane * 4;
    float o0 = fmaf(d0 * r, lg[c + 0], lb[c + 0]);
    float o1 = fmaf(d1 * r, lg[c + 1], lb[c + 1]);
    float o2 = fmaf(d2 * r, lg[c + 2], lb[c + 2]);
    float o3 = fmaf(d3 * r, lg[c + 3], lb[c + 3]);
    if (relu) {
        o0 = fmaxf(o0, 0.f); o1 = fmaxf(o1, 0.f); o2 = fmaxf(o2, 0.f); o3 = fmaxf(o3, 0.f);
    }
    __align__(8) bf16 tmp[4];
    tmp[0] = __float2bfloat16(o0);
    tmp[1] = __float2bfloat16(o1);
    tmp[2] = __float2bfloat16(o2);
    tmp[3] = __float2bfloat16(o3);
    *(uint2*)(h + base) = *(uint2*)tmp;
}

// ---------------- final: h (bf16 -> fp32) + scores; one wave per node ----------------
__global__ void k_out(const bf16* __restrict__ h, const float* __restrict__ sw,
                      const float* __restrict__ sb, float* __restrict__ out) {
    int gt = blockIdx.x * blockDim.x + threadIdx.x;
    int node = gt >> 6;
    int lane = gt & 63;
    size_t base = (size_t)node * 256 + lane * 4;
    uint2 uh = *(const uint2*)(h + base);
    float v0, v1, v2, v3;
    unpack2(uh.x, v0, v1);
    unpack2(uh.y, v2, v3);
    *(float4*)(out + base) = make_float4(v0, v1, v2, v3);
    int c = lane * 4;
    float part = v0 * sw[c + 0] + v1 * sw[c + 1] + v2 * sw[c + 2] + v3 * sw[c + 3];
#pragma unroll
    for (int off = 32; off > 0; off >>= 1) part += __shfl_xor(part, off, 64);
    if (lane == 0)
        out[(size_t)N_NODES * 256 + node] = part + sb[0];
}

extern "C" void kernel_launch(void* const* d_in, const int* in_sizes, int n_in,
                              void* d_out, int out_size, void* d_ws, size_t ws_size,
                              hipStream_t stream) {
    if (ws_size < (size_t)100663296) return;  // 96 MiB known-good budget

    const float* x     = (const float*)d_in[0];
    const int*   esrc  = (const int*)d_in[1];
    const int*   edst  = (const int*)d_in[2];
    const float* eattr = (const float*)d_in[3];

    // workspace: 5 bf16 buffers of NH (16 MiB each) = 80 MiB
    bf16* convb = (bf16*)d_ws;
    bf16* qb    = convb + NH;
    bf16* kb    = qb + NH;
    bf16* vb    = kb + NH;
    bf16* tb    = vb + NH;
    bf16* hb    = qb;   // h overlays dead q-region between layers
    bf16* pjb   = kb;   // proj overlays dead k-region
    bf16* xb    = vb;   // x-cast overlays v (dead until v-GEMM)

    // scratch inside d_out (fp32 out buffer 33.7 MB; fully overwritten by k_out):
    // per layer: iwb 768x256 bf16 | owb 256x256 bf16 | cwT 256x256 bf16 | bns/bnt fp32
    char* scr = (char*)d_out;
    const size_t LBYTES = 393216 + 131072 + 131072 + 2048;  // 657,408 B per layer
    int*   counts  = (int*)(scr + 2 * LBYTES);
    int*   offsets = counts + 32768;
    int*   cursor  = offsets + 32769;
    int*   srcp    = cursor + 32768;
    float* attrp   = (float*)(srcp + E_EDGES);

    // --- CSR build (edges shared by both layers) ---
    (void)hipMemsetAsync(counts, 0, 32768 * sizeof(int), stream);
    k_hist<<<E_EDGES / 256, 256, 0, stream>>>(edst, counts);
    k_scan<<<1, 256, 0, stream>>>(counts, offsets, cursor);
    k_fill<<<E_EDGES / 256, 256, 0, stream>>>(esrc, edst, eattr, cursor, srcp, attrp);

    // --- weight staging (bf16, [n][k] layout for MFMA B-operand) ---
    for (int L = 0; L < 2; ++L) {
        int bi = 5 + L * 11;
        char* base = scr + (size_t)L * LBYTES;
        bf16*  iwb = (bf16*)base;                 // 196608: q|k|v rows, already [n][k]
        bf16*  owb = iwb + 196608;                // 65536, already [n][k]
        bf16*  cwT = owb + 65536;                 // 65536, transpose of conv_w [k][n]
        float* bns = (float*)(cwT + 65536);
        float* bnt = bns + 256;
        k_cvtb4<<<192, 256, 0, stream>>>(iwb, (const float*)d_in[bi + 5]);
        k_cvtb4<<<64, 256, 0, stream>>>(owb, (const float*)d_in[bi + 7]);
        k_trb<<<256, 256, 0, stream>>>(cwT, (const float*)d_in[bi + 0]);
        k_bnprep<<<1, 256, 0, stream>>>(bns, bnt, (const float*)d_in[bi + 1],
                                        (const float*)d_in[bi + 2], (const float*)d_in[bi + 3],
                                        (const float*)d_in[bi + 4]);
    }

    // x -> bf16 (into v-region, dead until the v GEMM of layer 0)
    k_cvtb4<<<8192, 256, 0, stream>>>(xb, x);

    for (int L = 0; L < 2; ++L) {
        int bi = 5 + L * 11;
        char* base = scr + (size_t)L * LBYTES;
        bf16*  iwb = (bf16*)base;
        bf16*  owb = iwb + 196608;
        bf16*  cwT = owb + 65536;
        float* bns = (float*)(cwT + 65536);
        float* bnt = bns + 256;
        const float* ib = (const float*)d_in[bi + 6];
        const float* ob = (const float*)d_in[bi + 8];

        // t = (x or h) @ conv_w
        k_gemm<<<dim3(256, 2), 256, 0, stream>>>(L == 0 ? xb : hb, cwT, nullptr, tb);
        // conv[n] = BN( sum_{e: dst=n} attr_e * t[src_e] )  -- CSR gather
        k_gather<<<8192, 256, 0, stream>>>(tb, offsets, srcp, attrp, bns, bnt, convb);
        // q/k/v = conv @ iw[slice].T + bias
        k_gemm<<<dim3(256, 2), 256, 0, stream>>>(convb, iwb, ib, qb);
        k_gemm<<<dim3(256, 2), 256, 0, stream>>>(convb, iwb + 65536, ib + 256, kb);
        k_gemm<<<dim3(256, 2), 256, 0, stream>>>(convb, iwb + 131072, ib + 512, vb);
        // attention context -> t
        k_attn<<<512, 256, 0, stream>>>(qb, kb, vb, tb);
        // proj = ctx @ ow.T + ob
        k_gemm<<<dim3(256, 2), 256, 0, stream>>>(tb, owb, ob, pjb);
        // h = LN(conv + proj) (+ReLU on layer 0)
        k_ln<<<8192, 256, 0, stream>>>(convb, pjb, (const float*)d_in[bi + 9],
                                       (const float*)d_in[bi + 10], hb, L == 0 ? 1 : 0);
    }

    k_out<<<8192, 256, 0, stream>>>(hb, (const float*)d_in[27], (const float*)d_in[28],
                                    (float*)d_out);
}

// Round 9
// 691.869 us; speedup vs baseline: 7.2388x; 1.9063x over previous
//
#include <hip/hip_runtime.h>
#include <hip/hip_bf16.h>
#include <math.h>

#define N_NODES 32768
#define E_EDGES 524288
#define NHID    256
#define HEAD_DIM 64
#define SEQ     512
#define EPS_LN  1e-5f

typedef __hip_bfloat16 bf16;
typedef __attribute__((ext_vector_type(8))) short short8;   // 8 bf16 (4 VGPRs)
typedef __attribute__((ext_vector_type(4))) float floatx4;  // MFMA accumulator
static const size_t NH = (size_t)N_NODES * NHID;  // 8,388,608

__device__ __forceinline__ void unpack2(unsigned int u, float& lo, float& hi) {
    union { float f; unsigned int i; } a, b;
    a.i = u << 16; b.i = u & 0xffff0000u;
    lo = a.f; hi = b.f;
}

// ---------------- staging: fp32 -> bf16 casts ----------------
__global__ void k_cvtb4(bf16* __restrict__ dst, const float* __restrict__ src) {
    size_t i = (size_t)(blockIdx.x * 256 + threadIdx.x) * 4;
    const float4 v = *(const float4*)(src + i);
    __align__(8) bf16 tmp[4];
    tmp[0] = __float2bfloat16(v.x);
    tmp[1] = __float2bfloat16(v.y);
    tmp[2] = __float2bfloat16(v.z);
    tmp[3] = __float2bfloat16(v.w);
    *(uint2*)(dst + i) = *(uint2*)tmp;
}

// transpose+cast 256x256: dst[n*256+k] = bf16(src[k*256+n])
__global__ void k_trb(bf16* __restrict__ dst, const float* __restrict__ src) {
    int k = blockIdx.x, n = threadIdx.x;
    dst[(size_t)n * 256 + k] = __float2bfloat16(src[(size_t)k * 256 + n]);
}

// fold BN eval-mode into scale/shift: s = g*rsqrt(v+eps), t = b - m*s
__global__ void k_bnprep(float* __restrict__ s, float* __restrict__ t,
                         const float* g, const float* b, const float* m, const float* v) {
    int c = threadIdx.x;
    float sv = g[c] * rsqrtf(v[c] + EPS_LN);
    s[c] = sv;
    t[c] = b[c] - m[c] * sv;
}

// ---------------- CSR build: histogram -> scan -> fill ----------------
__global__ void k_hist(const int* __restrict__ edst, int* __restrict__ counts) {
    int e = blockIdx.x * 256 + threadIdx.x;
    atomicAdd(&counts[edst[e]], 1);
}

__global__ __launch_bounds__(256) void k_scan(const int* __restrict__ counts,
                                              int* __restrict__ offsets,
                                              int* __restrict__ cursor) {
    __shared__ int sums[256];
    const int tid = threadIdx.x;
    const int base = tid * 128;
    int s = 0;
    for (int i = 0; i < 128; ++i) s += counts[base + i];
    sums[tid] = s;
    __syncthreads();
    for (int off = 1; off < 256; off <<= 1) {
        int v = (tid >= off) ? sums[tid - off] : 0;
        __syncthreads();
        sums[tid] += v;
        __syncthreads();
    }
    int run = (tid == 0) ? 0 : sums[tid - 1];
    for (int i = 0; i < 128; ++i) {
        int c = counts[base + i];
        offsets[base + i] = run;
        cursor[base + i] = run;
        run += c;
    }
    if (tid == 255) offsets[32768] = run;
}

__global__ void k_fill(const int* __restrict__ esrc, const int* __restrict__ edst,
                       const float* __restrict__ eattr, int* __restrict__ cursor,
                       int* __restrict__ srcp, float* __restrict__ attrp) {
    int e = blockIdx.x * 256 + threadIdx.x;
    int d = edst[e];
    int slot = atomicAdd(&cursor[d], 1);
    srcp[slot] = esrc[e];
    attrp[slot] = eattr[e];
}

// ---------------- conv gather + fused BN: one wave per dst node; bf16 out ----------------
__global__ __launch_bounds__(256) void k_gather(const bf16* __restrict__ t,
                                                const int* __restrict__ offsets,
                                                const int* __restrict__ srcp,
                                                const float* __restrict__ attrp,
                                                const float* __restrict__ bns,
                                                const float* __restrict__ bnt,
                                                bf16* __restrict__ conv) {
    const int node = (blockIdx.x * 256 + threadIdx.x) >> 6;
    const int lane = threadIdx.x & 63;
    const int start = offsets[node];
    const int end = offsets[node + 1];
    float a0 = 0.f, a1 = 0.f, a2 = 0.f, a3 = 0.f;
    for (int c0 = start; c0 < end; c0 += 64) {
        const int n = min(64, end - c0);
        int sidx = 0;
        float sa = 0.f;
        if (lane < n) {
            sidx = srcp[c0 + lane];
            sa = attrp[c0 + lane];
        }
        for (int j = 0; j < n; ++j) {
            const int s = __shfl(sidx, j, 64);
            const float a = __shfl(sa, j, 64);
            uint2 u = *(const uint2*)(t + (size_t)s * 256 + lane * 4);
            float v0, v1, v2, v3;
            unpack2(u.x, v0, v1);
            unpack2(u.y, v2, v3);
            a0 = fmaf(a, v0, a0);
            a1 = fmaf(a, v1, a1);
            a2 = fmaf(a, v2, a2);
            a3 = fmaf(a, v3, a3);
        }
    }
    const int c = lane * 4;
    const float4 sv = *(const float4*)(bns + c);
    const float4 tv = *(const float4*)(bnt + c);
    __align__(8) bf16 tmp[4];
    tmp[0] = __float2bfloat16(fmaf(a0, sv.x, tv.x));
    tmp[1] = __float2bfloat16(fmaf(a1, sv.y, tv.y));
    tmp[2] = __float2bfloat16(fmaf(a2, sv.z, tv.z));
    tmp[3] = __float2bfloat16(fmaf(a3, sv.w, tv.w));
    *(uint2*)(conv + (size_t)node * 256 + c) = *(uint2*)tmp;
}

// ---------------- MFMA GEMM: C[32768x256] = A[32768x256] @ B, B staged as WT[n][k] bf16 ----
__global__ __launch_bounds__(256) void k_gemm(const bf16* __restrict__ A,
                                              const bf16* __restrict__ WT,
                                              const float* __restrict__ bias,
                                              bf16* __restrict__ C) {
    __shared__ __align__(16) short As[128][72];
    __shared__ __align__(16) short Bs[128][72];
    const int tid = threadIdx.x;
    const int bm = blockIdx.x * 128;
    const int bn = blockIdx.y * 128;
    const int wid = tid >> 6;
    const int lane = tid & 63;
    const int wr = (wid >> 1) * 64;
    const int wc = (wid & 1) * 64;
    const int quad = lane >> 4;
    const int l16 = lane & 15;

    floatx4 acc[4][4];
#pragma unroll
    for (int mi = 0; mi < 4; ++mi)
#pragma unroll
        for (int ni = 0; ni < 4; ++ni)
            acc[mi][ni] = (floatx4){0.f, 0.f, 0.f, 0.f};

    const int srow = tid >> 3;
    const int scol = (tid & 7) * 8;

    for (int k0 = 0; k0 < 256; k0 += 64) {
#pragma unroll
        for (int i = 0; i < 4; ++i) {
            const int row = srow + 32 * i;
            *(uint4*)&As[row][scol] = *(const uint4*)(A + (size_t)(bm + row) * 256 + k0 + scol);
            *(uint4*)&Bs[row][scol] = *(const uint4*)(WT + (size_t)(bn + row) * 256 + k0 + scol);
        }
        __syncthreads();
#pragma unroll
        for (int kk = 0; kk < 2; ++kk) {
            const int kcol = kk * 32 + quad * 8;
            short8 af[4], bfr[4];
#pragma unroll
            for (int mi = 0; mi < 4; ++mi) af[mi] = *(const short8*)&As[wr + mi * 16 + l16][kcol];
#pragma unroll
            for (int ni = 0; ni < 4; ++ni) bfr[ni] = *(const short8*)&Bs[wc + ni * 16 + l16][kcol];
#pragma unroll
            for (int mi = 0; mi < 4; ++mi)
#pragma unroll
                for (int ni = 0; ni < 4; ++ni)
                    acc[mi][ni] = __builtin_amdgcn_mfma_f32_16x16x32_bf16(af[mi], bfr[ni],
                                                                          acc[mi][ni], 0, 0, 0);
        }
        __syncthreads();
    }
#pragma unroll
    for (int ni = 0; ni < 4; ++ni) {
        const int gc = bn + wc + ni * 16 + l16;
        const float bv = bias ? bias[gc] : 0.f;
#pragma unroll
        for (int mi = 0; mi < 4; ++mi) {
            const int gr = bm + wr + mi * 16 + quad * 4;
#pragma unroll
            for (int r = 0; r < 4; ++r)
                C[(size_t)(gr + r) * 256 + gc] = __float2bfloat16(acc[mi][ni][r] + bv);
        }
    }
}

// ---------------- MFMA flash attention ----------------
// block = (graph, head, 64-row q-tile); 4 waves, each owns 16 q rows.
__global__ __launch_bounds__(256) void k_fattn(const bf16* __restrict__ qb,
                                               const bf16* __restrict__ kb,
                                               const bf16* __restrict__ vb,
                                               bf16* __restrict__ ctx) {
    const int qt = blockIdx.x & 7;
    const int head = (blockIdx.x >> 3) & 3;
    const int b = blockIdx.x >> 5;
    const int tid = threadIdx.x;
    const int wave = tid >> 6;
    const int lane = tid & 63;
    const int quad = lane >> 4;
    const int l16 = lane & 15;
    const int qrow0 = b * SEQ + qt * 64 + wave * 16;

    __shared__ __align__(16) short Ks[64][72];       // [key][d]
    __shared__ __align__(16) short Vt[64][72];       // [d][key]
    __shared__ __align__(16) short Ps[4][16][72];    // per-wave P tile [q][key]

    short8 af_q[2];
    {
        const bf16* qp = qb + (size_t)(qrow0 + l16) * 256 + head * HEAD_DIM + quad * 8;
        af_q[0] = *(const short8*)(qp);
        af_q[1] = *(const short8*)(qp + 32);
    }

    floatx4 acc[4];
#pragma unroll
    for (int nt = 0; nt < 4; ++nt) acc[nt] = (floatx4){0.f, 0.f, 0.f, 0.f};
    float m[4] = {-1e30f, -1e30f, -1e30f, -1e30f};
    float l[4] = {0.f, 0.f, 0.f, 0.f};

    const int kglob0 = b * SEQ;
    const int skey = tid >> 3;
    const int sd = (tid & 7) * 8;

    for (int kt = 0; kt < 8; ++kt) {
#pragma unroll
        for (int it = 0; it < 2; ++it) {
            const int key = skey + it * 32;
            const size_t goff = (size_t)(kglob0 + kt * 64 + key) * 256 + head * HEAD_DIM + sd;
            *(uint4*)&Ks[key][sd] = *(const uint4*)(kb + goff);
            const short8 v8 = *(const short8*)(vb + goff);
#pragma unroll
            for (int j = 0; j < 8; ++j) Vt[sd + j][key] = v8[j];
        }
        __syncthreads();

        floatx4 sf[4];
#pragma unroll
        for (int f = 0; f < 4; ++f) {
            const short8 bk0 = *(const short8*)&Ks[f * 16 + l16][quad * 8];
            const short8 bk1 = *(const short8*)&Ks[f * 16 + l16][32 + quad * 8];
            sf[f] = __builtin_amdgcn_mfma_f32_16x16x32_bf16(af_q[0], bk0,
                                                            (floatx4){0.f, 0.f, 0.f, 0.f}, 0, 0, 0);
            sf[f] = __builtin_amdgcn_mfma_f32_16x16x32_bf16(af_q[1], bk1, sf[f], 0, 0, 0);
        }

#pragma unroll
        for (int r = 0; r < 4; ++r) {
            float s0 = sf[0][r] * 0.125f;
            float s1 = sf[1][r] * 0.125f;
            float s2 = sf[2][r] * 0.125f;
            float s3 = sf[3][r] * 0.125f;
            float tmax = fmaxf(fmaxf(s0, s1), fmaxf(s2, s3));
            tmax = fmaxf(tmax, __shfl_xor(tmax, 1, 64));
            tmax = fmaxf(tmax, __shfl_xor(tmax, 2, 64));
            tmax = fmaxf(tmax, __shfl_xor(tmax, 4, 64));
            tmax = fmaxf(tmax, __shfl_xor(tmax, 8, 64));
            const float mnew = fmaxf(m[r], tmax);
            const float corr = __expf(m[r] - mnew);
            m[r] = mnew;
            const float p0 = __expf(s0 - mnew);
            const float p1 = __expf(s1 - mnew);
            const float p2 = __expf(s2 - mnew);
            const float p3 = __expf(s3 - mnew);
            float ps = p0 + p1 + p2 + p3;
            ps += __shfl_xor(ps, 1, 64);
            ps += __shfl_xor(ps, 2, 64);
            ps += __shfl_xor(ps, 4, 64);
            ps += __shfl_xor(ps, 8, 64);
            l[r] = l[r] * corr + ps;
#pragma unroll
            for (int nt = 0; nt < 4; ++nt) acc[nt][r] *= corr;
            // BUGFIX (R7/R8): Ps is short[]; `Ps[..] = __float2bfloat16(p)` silently did
            // float->short INTEGER truncation via bf16's operator float(). Store raw bits:
            bf16* psrow = (bf16*)&Ps[wave][quad * 4 + r][0];
            psrow[l16]      = __float2bfloat16(p0);
            psrow[16 + l16] = __float2bfloat16(p1);
            psrow[32 + l16] = __float2bfloat16(p2);
            psrow[48 + l16] = __float2bfloat16(p3);
        }

#pragma unroll
        for (int c = 0; c < 2; ++c) {
            const short8 ap = *(const short8*)&Ps[wave][l16][c * 32 + quad * 8];
#pragma unroll
            for (int nt = 0; nt < 4; ++nt) {
                const short8 bv = *(const short8*)&Vt[nt * 16 + l16][c * 32 + quad * 8];
                acc[nt] = __builtin_amdgcn_mfma_f32_16x16x32_bf16(ap, bv, acc[nt], 0, 0, 0);
            }
        }
        __syncthreads();
    }

#pragma unroll
    for (int r = 0; r < 4; ++r) {
        const float inv = 1.f / l[r];
        bf16* op = ctx + (size_t)(qrow0 + quad * 4 + r) * 256 + head * HEAD_DIM + l16;
        op[0]  = __float2bfloat16(acc[0][r] * inv);
        op[16] = __float2bfloat16(acc[1][r] * inv);
        op[32] = __float2bfloat16(acc[2][r] * inv);
        op[48] = __float2bfloat16(acc[3][r] * inv);
    }
}

// ---------------- residual + LayerNorm (+optional ReLU); one wave per node ----------------
__global__ void k_ln(const bf16* __restrict__ conv, const bf16* __restrict__ proj,
                     const float* __restrict__ lg, const float* __restrict__ lb,
                     bf16* __restrict__ h, int relu) {
    int gt = blockIdx.x * blockDim.x + threadIdx.x;
    int node = gt >> 6;
    int lane = gt & 63;
    size_t base = (size_t)node * 256 + lane * 4;
    uint2 ua = *(const uint2*)(conv + base);
    uint2 up = *(const uint2*)(proj + base);
    float a0, a1, a2, a3, p0, p1, p2, p3;
    unpack2(ua.x, a0, a1);
    unpack2(ua.y, a2, a3);
    unpack2(up.x, p0, p1);
    unpack2(up.y, p2, p3);
    float y0 = a0 + p0, y1 = a1 + p1, y2 = a2 + p2, y3 = a3 + p3;
    float sum = y0 + y1 + y2 + y3;
#pragma unroll
    for (int off = 32; off > 0; off >>= 1) sum += __shfl_xor(sum, off, 64);
    float mu = sum * (1.0f / 256.0f);
    float d0 = y0 - mu, d1 = y1 - mu, d2 = y2 - mu, d3 = y3 - mu;
    float vs = d0 * d0 + d1 * d1 + d2 * d2 + d3 * d3;
#pragma unroll
    for (int off = 32; off > 0; off >>= 1) vs += __shfl_xor(vs, off, 64);
    float r = rsqrtf(vs * (1.0f / 256.0f) + EPS_LN);
    int c = lane * 4;
    float o0 = fmaf(d0 * r, lg[c + 0], lb[c + 0]);
    float o1 = fmaf(d1 * r, lg[c + 1], lb[c + 1]);
    float o2 = fmaf(d2 * r, lg[c + 2], lb[c + 2]);
    float o3 = fmaf(d3 * r, lg[c + 3], lb[c + 3]);
    if (relu) {
        o0 = fmaxf(o0, 0.f); o1 = fmaxf(o1, 0.f); o2 = fmaxf(o2, 0.f); o3 = fmaxf(o3, 0.f);
    }
    __align__(8) bf16 tmp[4];
    tmp[0] = __float2bfloat16(o0);
    tmp[1] = __float2bfloat16(o1);
    tmp[2] = __float2bfloat16(o2);
    tmp[3] = __float2bfloat16(o3);
    *(uint2*)(h + base) = *(uint2*)tmp;
}

// ---------------- final: h (bf16 -> fp32) + scores; one wave per node ----------------
__global__ void k_out(const bf16* __restrict__ h, const float* __restrict__ sw,
                      const float* __restrict__ sb, float* __restrict__ out) {
    int gt = blockIdx.x * blockDim.x + threadIdx.x;
    int node = gt >> 6;
    int lane = gt & 63;
    size_t base = (size_t)node * 256 + lane * 4;
    uint2 uh = *(const uint2*)(h + base);
    float v0, v1, v2, v3;
    unpack2(uh.x, v0, v1);
    unpack2(uh.y, v2, v3);
    *(float4*)(out + base) = make_float4(v0, v1, v2, v3);
    int c = lane * 4;
    float part = v0 * sw[c + 0] + v1 * sw[c + 1] + v2 * sw[c + 2] + v3 * sw[c + 3];
#pragma unroll
    for (int off = 32; off > 0; off >>= 1) part += __shfl_xor(part, off, 64);
    if (lane == 0)
        out[(size_t)N_NODES * 256 + node] = part + sb[0];
}

extern "C" void kernel_launch(void* const* d_in, const int* in_sizes, int n_in,
                              void* d_out, int out_size, void* d_ws, size_t ws_size,
                              hipStream_t stream) {
    if (ws_size < (size_t)100663296) return;  // 96 MiB known-good budget

    const float* x     = (const float*)d_in[0];
    const int*   esrc  = (const int*)d_in[1];
    const int*   edst  = (const int*)d_in[2];
    const float* eattr = (const float*)d_in[3];

    bf16* convb = (bf16*)d_ws;
    bf16* qb    = convb + NH;
    bf16* kb    = qb + NH;
    bf16* vb    = kb + NH;
    bf16* tb    = vb + NH;
    bf16* hb    = qb;   // h overlays dead q-region between layers
    bf16* pjb   = kb;   // proj overlays dead k-region
    bf16* xb    = vb;   // x-cast overlays v (dead until v-GEMM)

    char* scr = (char*)d_out;
    const size_t LBYTES = 393216 + 131072 + 131072 + 2048;
    int*   counts  = (int*)(scr + 2 * LBYTES);
    int*   offsets = counts + 32768;
    int*   cursor  = offsets + 32769;
    int*   srcp    = cursor + 32768;
    float* attrp   = (float*)(srcp + E_EDGES);

    (void)hipMemsetAsync(counts, 0, 32768 * sizeof(int), stream);
    k_hist<<<E_EDGES / 256, 256, 0, stream>>>(edst, counts);
    k_scan<<<1, 256, 0, stream>>>(counts, offsets, cursor);
    k_fill<<<E_EDGES / 256, 256, 0, stream>>>(esrc, edst, eattr, cursor, srcp, attrp);

    for (int L = 0; L < 2; ++L) {
        int bi = 5 + L * 11;
        char* base = scr + (size_t)L * LBYTES;
        bf16*  iwb = (bf16*)base;
        bf16*  owb = iwb + 196608;
        bf16*  cwT = owb + 65536;
        float* bns = (float*)(cwT + 65536);
        float* bnt = bns + 256;
        k_cvtb4<<<192, 256, 0, stream>>>(iwb, (const float*)d_in[bi + 5]);
        k_cvtb4<<<64, 256, 0, stream>>>(owb, (const float*)d_in[bi + 7]);
        k_trb<<<256, 256, 0, stream>>>(cwT, (const float*)d_in[bi + 0]);
        k_bnprep<<<1, 256, 0, stream>>>(bns, bnt, (const float*)d_in[bi + 1],
                                        (const float*)d_in[bi + 2], (const float*)d_in[bi + 3],
                                        (const float*)d_in[bi + 4]);
    }

    k_cvtb4<<<8192, 256, 0, stream>>>(xb, x);

    for (int L = 0; L < 2; ++L) {
        int bi = 5 + L * 11;
        char* base = scr + (size_t)L * LBYTES;
        bf16*  iwb = (bf16*)base;
        bf16*  owb = iwb + 196608;
        bf16*  cwT = owb + 65536;
        float* bns = (float*)(cwT + 65536);
        float* bnt = bns + 256;
        const float* ib = (const float*)d_in[bi + 6];
        const float* ob = (const float*)d_in[bi + 8];

        k_gemm<<<dim3(256, 2), 256, 0, stream>>>(L == 0 ? xb : hb, cwT, nullptr, tb);
        k_gather<<<8192, 256, 0, stream>>>(tb, offsets, srcp, attrp, bns, bnt, convb);
        k_gemm<<<dim3(256, 2), 256, 0, stream>>>(convb, iwb, ib, qb);
        k_gemm<<<dim3(256, 2), 256, 0, stream>>>(convb, iwb + 65536, ib + 256, kb);
        k_gemm<<<dim3(256, 2), 256, 0, stream>>>(convb, iwb + 131072, ib + 512, vb);
        k_fattn<<<2048, 256, 0, stream>>>(qb, kb, vb, tb);
        k_gemm<<<dim3(256, 2), 256, 0, stream>>>(tb, owb, ob, pjb);
        k_ln<<<8192, 256, 0, stream>>>(convb, pjb, (const float*)d_in[bi + 9],
                                       (const float*)d_in[bi + 10], hb, L == 0 ? 1 : 0);
    }

    k_out<<<8192, 256, 0, stream>>>(hb, (const float*)d_in[27], (const float*)d_in[28],
                                    (float*)d_out);
}